// Round 1
// 445.490 us; speedup vs baseline: 1.0648x; 1.0648x over previous
//
#include <hip/hip_runtime.h>
#include <math.h>

#define BB 4
#define HH 16
#define SS 1024
#define DD 64
#define QT 16     // q rows per block
#define NKW 4     // waves per block, each owns KPW k-columns
#define KPW 256
#define HPB 8     // heads per block (loop inside, bias reused from registers)

typedef __attribute__((ext_vector_type(8))) short bf16x8;
typedef __attribute__((ext_vector_type(4))) float f32x4;

static __device__ inline unsigned short f2bf(float f) {
    unsigned int u = __float_as_uint(f);
    u += 0x7fff + ((u >> 16) & 1);   // RNE
    return (unsigned short)(u >> 16);
}

// ---- pre-pass: fp32 -> bf16 for Q and K (row-major unchanged) ----
__global__ __launch_bounds__(256) void convert_qk(const float* __restrict__ q,
                                                  const float* __restrict__ k,
                                                  unsigned short* __restrict__ qb,
                                                  unsigned short* __restrict__ kb) {
    const int idx = blockIdx.x * 256 + threadIdx.x;     // 1,048,576 float4s
    float4 qv = ((const float4*)q)[idx];
    float4 kv = ((const float4*)k)[idx];
    ushort4 qo = make_ushort4(f2bf(qv.x), f2bf(qv.y), f2bf(qv.z), f2bf(qv.w));
    ushort4 ko = make_ushort4(f2bf(kv.x), f2bf(kv.y), f2bf(kv.z), f2bf(kv.w));
    ((ushort4*)qb)[idx] = qo;
    ((ushort4*)kb)[idx] = ko;
}

// ---- pre-pass: V [bh][k][d] fp32 -> Vt [bh][d][k] bf16, LDS-tiled ----
// Coalesced float4 reads, transpose via LDS, coalesced 16B writes.
__global__ __launch_bounds__(256) void transpose_v(const float* __restrict__ v,
                                                   unsigned short* __restrict__ vt) {
    __shared__ unsigned short t[DD][258];   // stride 258 ushorts: 4B-aligned, conflict-light
    const int bh = blockIdx.y;
    const int k0 = blockIdx.x * 256;
    const float* vb = v + ((size_t)bh * SS + k0) * DD;
#pragma unroll
    for (int j = 0; j < 16; ++j) {
        const int f   = j * 256 + threadIdx.x;   // float4 index within 256x64 tile
        const int row = f >> 4;                  // 16 float4 per k-row
        const int d4  = (f & 15) << 2;
        float4 x = ((const float4*)vb)[f];
        t[d4 + 0][row] = f2bf(x.x);
        t[d4 + 1][row] = f2bf(x.y);
        t[d4 + 2][row] = f2bf(x.z);
        t[d4 + 3][row] = f2bf(x.w);
    }
    __syncthreads();
    unsigned short* vo = vt + (size_t)bh * DD * SS + k0;
#pragma unroll
    for (int j = 0; j < 8; ++j) {
        const int f  = j * 256 + threadIdx.x;    // 16B-chunk index: 64 d x 32 chunks
        const int d  = f >> 5;
        const int k8 = (f & 31) << 3;
        const unsigned int* lp = (const unsigned int*)&t[d][k8];  // 4B-aligned
        uint4 w;
        w.x = lp[0]; w.y = lp[1]; w.z = lp[2]; w.w = lp[3];
        *(uint4*)(vo + (size_t)d * SS + k8) = w;
    }
}

// ---- main: block = (b, hg, 16-row q-tile); loops 8 heads, bias held in regs ----
__global__ __launch_bounds__(256, 2) void attn_mfma(
    const unsigned short* __restrict__ qb,   // [BH][S][D] bf16
    const unsigned short* __restrict__ kb,   // [BH][S][D] bf16
    const unsigned short* __restrict__ vtb,  // [BH][D][S] bf16
    const float* __restrict__ add_attn,      // [B][S][S]
    const int*   __restrict__ mask,          // [B][S]
    float* __restrict__ out,                 // [BH][S][D]
    float* __restrict__ attn_out)            // [BH][S][S]
{
    const int qt = blockIdx.x, hg = blockIdx.y, b = blockIdx.z;
    const int tid = threadIdx.x;
    const int wave = tid >> 6;
    const int lane = tid & 63;
    const int col  = lane & 15;      // MFMA C/D col, A-m, B-n
    const int quad = lane >> 4;

    __shared__ unsigned short p_tile[NKW][QT][KPW + 8];
    __shared__ float red_m[NKW][QT];
    __shared__ float red_l[NKW][QT];
    __shared__ float o_part[NKW][QT][DD];

    const int q0  = qt * QT;
    const int wk0 = wave * KPW;

    // ---- load bias tile once, fold mask (-1e9), keep in registers across heads ----
    const float* bias = add_attn + ((size_t)b * SS + q0) * SS;
    const int*   mrow = mask + b * SS;
    float br[16][4];
#pragma unroll
    for (int t = 0; t < 16; ++t) {
        const int kidx = wk0 + t * 16 + col;
        const int mv = mrow[kidx];
#pragma unroll
        for (int r = 0; r < 4; ++r) {
            const int qr = quad * 4 + r;
            float bv = bias[(size_t)qr * SS + kidx];
            br[t][r] = mv ? bv : -1e9f;
        }
    }

    for (int hi = 0; hi < HPB; ++hi) {
        const int h  = hg * HPB + hi;
        const int bh = b * HH + h;

        // A-frags for QK^T: Q[q0+col][quad*8+j (+32)]
        const unsigned short* qrow = qb + ((size_t)bh * SS + q0 + col) * DD + quad * 8;
        const bf16x8 aq0 = *(const bf16x8*)(qrow);
        const bf16x8 aq1 = *(const bf16x8*)(qrow + 32);

        const unsigned short* kbb = kb + (size_t)bh * SS * DD;

        // ---- QK^T: 16 k-tiles of 16, scores kept in regs (C layout) ----
        float s[16][4];
#pragma unroll
        for (int t = 0; t < 16; ++t) {
            const int k0 = wk0 + t * 16;
            const unsigned short* kr = kbb + (size_t)(k0 + col) * DD + quad * 8;
            bf16x8 bk0 = *(const bf16x8*)(kr);
            bf16x8 bk1 = *(const bf16x8*)(kr + 32);
            f32x4 acc = {0.f, 0.f, 0.f, 0.f};
            acc = __builtin_amdgcn_mfma_f32_16x16x32_bf16(aq0, bk0, acc, 0, 0, 0);
            acc = __builtin_amdgcn_mfma_f32_16x16x32_bf16(aq1, bk1, acc, 0, 0, 0);
#pragma unroll
            for (int r = 0; r < 4; ++r)
                s[t][r] = acc[r] * 0.125f + br[t][r];   // masked: ~-1e9, exp -> 0
        }

        // ---- row max: per-lane over t, xor-shuffle over the 16-lane col group ----
        float mx[4];
#pragma unroll
        for (int r = 0; r < 4; ++r) {
            float m = s[0][r];
#pragma unroll
            for (int t = 1; t < 16; ++t) m = fmaxf(m, s[t][r]);
            m = fmaxf(m, __shfl_xor(m, 1));
            m = fmaxf(m, __shfl_xor(m, 2));
            m = fmaxf(m, __shfl_xor(m, 4));
            m = fmaxf(m, __shfl_xor(m, 8));
            mx[r] = m;
        }
        if (col == 0) {
#pragma unroll
            for (int r = 0; r < 4; ++r) red_m[wave][quad * 4 + r] = mx[r];
        }
        __syncthreads();
        float mf[4];
#pragma unroll
        for (int r = 0; r < 4; ++r) {
            const int qr = quad * 4 + r;
            mf[r] = fmaxf(fmaxf(red_m[0][qr], red_m[1][qr]),
                          fmaxf(red_m[2][qr], red_m[3][qr]));
        }

        // ---- exp + row sum ----
        float ls[4] = {0.f, 0.f, 0.f, 0.f};
#pragma unroll
        for (int t = 0; t < 16; ++t) {
#pragma unroll
            for (int r = 0; r < 4; ++r) {
                float e = __expf(s[t][r] - mf[r]);
                s[t][r] = e;
                ls[r] += e;
            }
        }
#pragma unroll
        for (int r = 0; r < 4; ++r) {
            float l = ls[r];
            l += __shfl_xor(l, 1);
            l += __shfl_xor(l, 2);
            l += __shfl_xor(l, 4);
            l += __shfl_xor(l, 8);
            ls[r] = l;
        }
        if (col == 0) {
#pragma unroll
            for (int r = 0; r < 4; ++r) red_l[wave][quad * 4 + r] = ls[r];
        }
        __syncthreads();
        float inv[4];
#pragma unroll
        for (int r = 0; r < 4; ++r) {
            const int qr = quad * 4 + r;
            inv[r] = 1.0f / (red_l[0][qr] + red_l[1][qr] + red_l[2][qr] + red_l[3][qr]);
        }

        // ---- normalize, write attn (fp32, non-temporal) + p_tile (bf16) ----
        float* arow = attn_out + ((size_t)bh * SS + q0) * SS;
#pragma unroll
        for (int t = 0; t < 16; ++t) {
#pragma unroll
            for (int r = 0; r < 4; ++r) {
                const int qr = quad * 4 + r;
                float p = s[t][r] * inv[r];
                __builtin_nontemporal_store(p, &arow[(size_t)qr * SS + wk0 + t * 16 + col]);
                p_tile[wave][qr][t * 16 + col] = f2bf(p);
            }
        }

        // ---- PV: A = p_tile (wave-local), B = Vt contiguous 16B loads ----
        const unsigned short* vt = vtb + (size_t)bh * DD * SS;
        f32x4 oacc[4];
#pragma unroll
        for (int dc = 0; dc < 4; ++dc) oacc[dc] = (f32x4){0.f, 0.f, 0.f, 0.f};
#pragma unroll
        for (int c = 0; c < 8; ++c) {
            bf16x8 ap = *(const bf16x8*)(&p_tile[wave][col][c * 32 + quad * 8]);
#pragma unroll
            for (int dc = 0; dc < 4; ++dc) {
                const unsigned short* vr =
                    vt + (size_t)(dc * 16 + col) * SS + wk0 + c * 32 + quad * 8;
                bf16x8 bv = *(const bf16x8*)(vr);
                oacc[dc] = __builtin_amdgcn_mfma_f32_16x16x32_bf16(ap, bv, oacc[dc], 0, 0, 0);
            }
        }
#pragma unroll
        for (int dc = 0; dc < 4; ++dc)
#pragma unroll
            for (int r = 0; r < 4; ++r)
                o_part[wave][quad * 4 + r][dc * 16 + col] = oacc[dc][r];
        __syncthreads();

        // ---- cross-wave sum + out write ----
        for (int i = tid; i < QT * DD; i += 256) {
            const int qr = i >> 6, d = i & 63;
            float ov = o_part[0][qr][d] + o_part[1][qr][d] +
                       o_part[2][qr][d] + o_part[3][qr][d];
            __builtin_nontemporal_store(ov, &out[((size_t)bh * SS + q0 + qr) * DD + d]);
        }
        __syncthreads();   // protect red_m/o_part before next head reuses them
    }
}

extern "C" void kernel_launch(void* const* d_in, const int* in_sizes, int n_in,
                              void* d_out, int out_size, void* d_ws, size_t ws_size,
                              hipStream_t stream) {
    const float* q        = (const float*)d_in[0];
    const float* k        = (const float*)d_in[1];
    const float* v        = (const float*)d_in[2];
    const float* add_attn = (const float*)d_in[3];
    const int*   mask     = (const int*)d_in[4];

    float* out      = (float*)d_out;
    float* attn_out = (float*)d_out + (size_t)BB * HH * SS * DD;

    const size_t nelem = (size_t)BB * HH * SS * DD;     // 4,194,304
    unsigned short* qb  = (unsigned short*)d_ws;
    unsigned short* kbb = qb + nelem;
    unsigned short* vtb = kbb + nelem;

    convert_qk<<<dim3(nelem / 4 / 256), dim3(256), 0, stream>>>(q, k, qb, kbb);
    transpose_v<<<dim3(SS / 256, BB * HH), dim3(256), 0, stream>>>(v, vtb);

    dim3 grid(SS / QT, 2, BB);
    attn_mfma<<<grid, dim3(256), 0, stream>>>(qb, kbb, vtb, add_attn, mask, out, attn_out);
}